// Round 8
// baseline (2978.726 us; speedup 1.0000x reference)
//
#include <hip/hip_runtime.h>

#define NL 12
#define DM 256
#define FFDIM 1024
#define BBATCH 32
#define LSEQ 448
#define MTOK (BBATCH*LSEQ)     // 14336
#define EPSF 1e-6f
// 1/sqrt(32) * log2(e): Q pre-scale so attn can use exp2 directly
#define QSCALE_LOG2E (0.17677669529663687f * 1.4426950408889634f)

typedef __attribute__((ext_vector_type(8))) short bf16x8;
typedef __attribute__((ext_vector_type(4))) float f32x4;
typedef unsigned short u16;
typedef unsigned int u32;

__device__ __forceinline__ u16 f2bf(float f) {
    union { float f; u32 u; } v; v.f = f;
    u32 r = v.u + 0x7fffu + ((v.u >> 16) & 1u);
    return (u16)(r >> 16);
}
__device__ __forceinline__ float gelu_exact(float x) {
    return 0.5f * x * (1.0f + erff(x * 0.70710678118654752f));
}
__device__ __forceinline__ void gload16(const u16* g, u16* l) {
    __builtin_amdgcn_global_load_lds(
        (const __attribute__((address_space(1))) u32*)g,
        (__attribute__((address_space(3))) u32*)l, 16, 0, 0);
}

// ---------------------------------------------------------------------------
__global__ __launch_bounds__(256) void add_pos_k(
    const float* __restrict__ x, const float* __restrict__ pe, float* __restrict__ out)
{
    int i = blockIdx.x * 256 + threadIdx.x;
    float4 xv = ((const float4*)x)[i];
    float4 pv = ((const float4*)pe)[i % (LSEQ * DM / 4)];
    float4 r;
    r.x = xv.x + pv.x; r.y = xv.y + pv.y; r.z = xv.z + pv.z; r.w = xv.w + pv.w;
    ((float4*)out)[i] = r;
}

// ---------------------------------------------------------------------------
// Weight transpose + cvt: fp32 [layer][K][N] -> bf16 [layer][N][K]
__global__ __launch_bounds__(256) void twt_k(
    const float* __restrict__ in, u16* __restrict__ out,
    int K, int N, int in_lstride, int out_lstride)
{
    __shared__ float tl[32][33];
    const int l = blockIdx.z;
    const int n0 = blockIdx.x * 32, k0 = blockIdx.y * 32;
    const int tx = threadIdx.x & 31, ty = threadIdx.x >> 5;
    const float* src = in + (size_t)l * in_lstride;
#pragma unroll
    for (int i = 0; i < 4; ++i)
        tl[ty + 8*i][tx] = src[(size_t)(k0 + ty + 8*i) * N + n0 + tx];
    __syncthreads();
    u16* dst = out + (size_t)l * out_lstride;
#pragma unroll
    for (int i = 0; i < 4; ++i)
        dst[(size_t)(n0 + ty + 8*i) * K + k0 + tx] = f2bf(tl[tx][ty + 8*i]);
}

__global__ __launch_bounds__(256) void pack_bias_k(
    const float* __restrict__ bq, const float* __restrict__ bk,
    const float* __restrict__ bv, float* __restrict__ bqkv)
{
    int i = blockIdx.x * 256 + threadIdx.x;
    if (i >= NL * 768) return;
    int l = i / 768, c = i % 768;
    float v = (c < 256) ? bq[l*256 + c] : (c < 512) ? bk[l*256 + c - 256] : bv[l*256 + c - 512];
    bqkv[i] = v;
}

// ---------------------------------------------------------------------------
// LN-fused bf16 MFMA GEMM: C = LN(X) @ Bt^T + bias.  BM=128, BN=64, K=256.
// LN computed in prologue into resident As[128][264] (padded); K-loop stages
// only B via global_load_lds. Wave tile 32x64 (MT=2, NT=4).
// EPI 0 = QKV: cols<256 Q*QSCALE_LOG2E -> C; 256..511 K -> C;
//              512..767 V packed ushort4 -> vtg[b][h][d][s]
// EPI 1 = FF1: gelu -> C
template<int EPI>
__global__ __launch_bounds__(256, 2) void mmln_k(
    const float* __restrict__ X, const float* __restrict__ g,
    const float* __restrict__ b, const u16* __restrict__ Bt,
    const float* __restrict__ bias, u16* __restrict__ C, int ldc,
    u16* __restrict__ vtg)
{
    __shared__ u16 As[128 * 264];
    __shared__ u16 Bs[2][64 * 32];
    const int tid = threadIdx.x;
    const int by = blockIdx.x, bx = blockIdx.y;   // by = M-block (XCD pin)
    const int w = tid >> 6, lane = tid & 63;
    const int lm = lane & 15, lk = lane >> 4;
    const int m0 = w * 32;
    const int lrow = lane >> 2, lcol = (lane & 3) * 8;

    // ---- LN prologue: rows w*32..w*32+31, lane covers 4 cols ----
    float4 gv4 = ((const float4*)g)[lane];
    float4 bv4 = ((const float4*)b)[lane];
    for (int i = 0; i < 32; ++i) {
        int row = m0 + i;
        float4 xv = *(const float4*)(X + (size_t)(by * 128 + row) * 256 + lane * 4);
        float s = xv.x + xv.y + xv.z + xv.w;
#pragma unroll
        for (int off = 32; off; off >>= 1) s += __shfl_xor(s, off);
        float mu = s * (1.0f / 256.0f);
        float d0 = xv.x - mu, d1 = xv.y - mu, d2 = xv.z - mu, d3 = xv.w - mu;
        float sq = d0*d0 + d1*d1 + d2*d2 + d3*d3;
#pragma unroll
        for (int off = 32; off; off >>= 1) sq += __shfl_xor(sq, off);
        float rs = rsqrtf(sq * (1.0f / 256.0f) + EPSF);
        ushort4 o;
        o.x = f2bf(d0 * rs * gv4.x + bv4.x);
        o.y = f2bf(d1 * rs * gv4.y + bv4.y);
        o.z = f2bf(d2 * rs * gv4.z + bv4.z);
        o.w = f2bf(d3 * rs * gv4.w + bv4.w);
        *(ushort4*)&As[row * 264 + lane * 4] = o;
    }

    const u16* Bb = Bt + (size_t)(bx * 64) * 256;
    f32x4 zz = {0.f, 0.f, 0.f, 0.f};
    f32x4 acc[2][4];
#pragma unroll
    for (int i = 0; i < 2; ++i)
#pragma unroll
        for (int j = 0; j < 4; ++j) acc[i][j] = zz;

    for (int k0 = 0; k0 < 256; k0 += 64) {
        __syncthreads();   // first iter: As complete; later: Bs consumed
        gload16(Bb + (size_t)(w * 16 + lrow) * 256 + k0 + lcol,      &Bs[0][w * 512]);
        gload16(Bb + (size_t)(w * 16 + lrow) * 256 + k0 + 32 + lcol, &Bs[1][w * 512]);
        __syncthreads();
#pragma unroll
        for (int p = 0; p < 2; ++p) {
            bf16x8 af[2], bfr[4];
#pragma unroll
            for (int mt = 0; mt < 2; ++mt)
                af[mt] = *(const bf16x8*)&As[(m0 + mt*16 + lm) * 264 + k0 + p*32 + lk*8];
#pragma unroll
            for (int nt = 0; nt < 4; ++nt)
                bfr[nt] = *(const bf16x8*)&Bs[p][(nt*16 + lm) * 32 + lk*8];
#pragma unroll
            for (int mt = 0; mt < 2; ++mt)
#pragma unroll
                for (int nt = 0; nt < 4; ++nt)
                    acc[mt][nt] = __builtin_amdgcn_mfma_f32_16x16x32_bf16(af[mt], bfr[nt], acc[mt][nt], 0, 0, 0);
        }
    }

    float bv[4];
#pragma unroll
    for (int nt = 0; nt < 4; ++nt) bv[nt] = bias[bx*64 + nt*16 + lm];
#pragma unroll
    for (int mt = 0; mt < 2; ++mt) {
        int grow0 = by*128 + m0 + mt*16 + lk*4;
#pragma unroll
        for (int nt = 0; nt < 4; ++nt) {
            int gcol = bx*64 + nt*16 + lm;
            float v0 = acc[mt][nt][0] + bv[nt];
            float v1 = acc[mt][nt][1] + bv[nt];
            float v2 = acc[mt][nt][2] + bv[nt];
            float v3 = acc[mt][nt][3] + bv[nt];
            if constexpr (EPI == 1) {
                u16* cp = C + (size_t)grow0 * ldc + gcol;
                cp[0]       = f2bf(gelu_exact(v0));
                cp[ldc]     = f2bf(gelu_exact(v1));
                cp[2*ldc]   = f2bf(gelu_exact(v2));
                cp[3*ldc]   = f2bf(gelu_exact(v3));
            } else {
                if (gcol < 512) {
                    float qs = (gcol < 256) ? QSCALE_LOG2E : 1.0f;
                    u16* cp = C + (size_t)grow0 * ldc + gcol;
                    cp[0]     = f2bf(v0 * qs);
                    cp[ldc]   = f2bf(v1 * qs);
                    cp[2*ldc] = f2bf(v2 * qs);
                    cp[3*ldc] = f2bf(v3 * qs);
                } else {
                    int c = gcol - 512;
                    int hh = c >> 5, d = c & 31;
                    u32 bidx = (u32)grow0 / 448u;
                    int srow = grow0 - (int)bidx * 448;
                    ushort4 st;
                    st.x = f2bf(v0); st.y = f2bf(v1); st.z = f2bf(v2); st.w = f2bf(v3);
                    *(ushort4*)&vtg[((size_t)(bidx*8 + hh)*32 + d)*448 + srow] = st;
                }
            }
        }
    }
}

// ---------------------------------------------------------------------------
// bf16 MFMA GEMM: C = A[M,K] @ Bt[N,K]^T + bias. BM=128, BN=64, BK=64.
// 4 waves stacked in M, 32x64 each (MT=2). EPI 2 = fp32 residual +=.
template<int EPI>
__global__ __launch_bounds__(256, 4) void mm_k(
    const u16* __restrict__ A, int lda, const u16* __restrict__ Bt,
    const float* __restrict__ bias, void* __restrict__ C, int ldc, int K)
{
    __shared__ u16 As[2 * 128 * 32];
    __shared__ u16 Bs[2 * 64 * 32];
    const int tid = threadIdx.x;
    const int by = blockIdx.x, bx = blockIdx.y;
    const int w = tid >> 6, lane = tid & 63;
    const int lm = lane & 15, lk = lane >> 4;
    const int m0 = w * 32;
    const int lrow = lane >> 2, lcol = (lane & 3) * 8;

    const u16* Ab = A + (size_t)(by * 128) * lda;
    const u16* Bb = Bt + (size_t)(bx * 64) * K;

    f32x4 zz = {0.f, 0.f, 0.f, 0.f};
    f32x4 acc[2][4];
#pragma unroll
    for (int i = 0; i < 2; ++i)
#pragma unroll
        for (int j = 0; j < 4; ++j) acc[i][j] = zz;

    for (int k0 = 0; k0 < K; k0 += 64) {
        __syncthreads();
#pragma unroll
        for (int p = 0; p < 2; ++p) {
#pragma unroll
            for (int i = 0; i < 2; ++i) {
                int seg = w * 2 + i;
                gload16(Ab + (size_t)(seg * 16 + lrow) * lda + k0 + p * 32 + lcol,
                        &As[p * 4096 + seg * 512]);
            }
            gload16(Bb + (size_t)(w * 16 + lrow) * K + k0 + p * 32 + lcol,
                    &Bs[p * 2048 + w * 512]);
        }
        __syncthreads();
#pragma unroll
        for (int p = 0; p < 2; ++p) {
            bf16x8 af[2], bfr[4];
#pragma unroll
            for (int mt = 0; mt < 2; ++mt)
                af[mt] = *(const bf16x8*)&As[p * 4096 + (m0 + mt*16 + lm)*32 + lk*8];
#pragma unroll
            for (int nt = 0; nt < 4; ++nt)
                bfr[nt] = *(const bf16x8*)&Bs[p * 2048 + (nt*16 + lm)*32 + lk*8];
#pragma unroll
            for (int mt = 0; mt < 2; ++mt)
#pragma unroll
                for (int nt = 0; nt < 4; ++nt)
                    acc[mt][nt] = __builtin_amdgcn_mfma_f32_16x16x32_bf16(af[mt], bfr[nt], acc[mt][nt], 0, 0, 0);
        }
    }

    float bv[4];
#pragma unroll
    for (int nt = 0; nt < 4; ++nt) bv[nt] = bias[bx*64 + nt*16 + lm];
#pragma unroll
    for (int mt = 0; mt < 2; ++mt) {
#pragma unroll
        for (int r = 0; r < 4; ++r) {
            int grow = by*128 + m0 + mt*16 + lk*4 + r;
#pragma unroll
            for (int nt = 0; nt < 4; ++nt) {
                int gcol = bx*64 + nt*16 + lm;
                float vv = acc[mt][nt][r] + bv[nt];
                float* p = (float*)C + (size_t)grow * ldc + gcol;
                *p += vv;
            }
        }
    }
}

// ---------------------------------------------------------------------------
// MFMA attention, single-pass, no max subtraction (scores O(0.1); softmax is
// shift-invariant; masked keys -> p = 0 exactly). Q pre-scaled by
// 1/sqrt(dk)*log2(e) -> exp2f. Grid bid = sg*256 + bh (XCD pin).
__global__ __launch_bounds__(256, 4) void attn_k(
    const u16* __restrict__ qkv, const u16* __restrict__ vtg,
    const unsigned char* __restrict__ mask, u16* __restrict__ ob)
{
    __shared__ u16 Klds[448 * 32];
    __shared__ u16 Plds[4][16 * 68];
    const int tid = threadIdx.x, w = tid >> 6, lane = tid & 63;
    const int lm = lane & 15, lk = lane >> 4;
    const int bid = blockIdx.x;
    const int bh = bid & 255, sg = bid >> 8;
    const int b = bh >> 3, h = bh & 7;
    const size_t rowbase = (size_t)b * LSEQ;

#pragma unroll
    for (int i = 0; i < 7; ++i) {
        int seg = w * 7 + i;
        gload16(qkv + (rowbase + seg * 16 + (lane >> 2)) * 768 + 256 + h * 32 + (lane & 3) * 8,
                &Klds[seg * 512]);
    }
    unsigned mbits = 0;
#pragma unroll
    for (int t = 0; t < 28; ++t)
        mbits |= (mask[b * LSEQ + t * 16 + lm] ? 1u : 0u) << t;
    __syncthreads();

    const u16* Vb = vtg + (size_t)bh * 32 * 448;
    f32x4 zz = {0.f, 0.f, 0.f, 0.f};

    const int q0 = (sg * 4 + w) * 16;
    bf16x8 qf = *(const bf16x8*)(qkv + (rowbase + q0 + lm) * 768 + h * 32 + lk * 8);

    f32x4 oacc[2] = {zz, zz};
    float sum[4] = {0.f, 0.f, 0.f, 0.f};
    u16* P = &Plds[w][0];
#pragma unroll
    for (int cc = 0; cc < 7; ++cc) {
#pragma unroll
        for (int tt = 0; tt < 4; ++tt) {
            int t = cc*4 + tt;
            bf16x8 kf = *(const bf16x8*)&Klds[(t*16 + lm)*32 + lk*8];
            f32x4 s = __builtin_amdgcn_mfma_f32_16x16x32_bf16(qf, kf, zz, 0, 0, 0);
            bool m = (mbits >> t) & 1;
#pragma unroll
            for (int r = 0; r < 4; ++r) {
                float e = m ? 0.f : exp2f(s[r]);
                sum[r] += e;
                P[(lk*4 + r)*68 + tt*16 + lm] = f2bf(e);
            }
        }
        bf16x8 pa0 = *(const bf16x8*)&P[lm*68 + lk*8];
        bf16x8 pa1 = *(const bf16x8*)&P[lm*68 + 32 + lk*8];
#pragma unroll
        for (int dt = 0; dt < 2; ++dt) {
            bf16x8 vb0 = *(const bf16x8*)(Vb + (size_t)(dt*16 + lm)*448 + cc*64 + lk*8);
            bf16x8 vb1 = *(const bf16x8*)(Vb + (size_t)(dt*16 + lm)*448 + cc*64 + 32 + lk*8);
            oacc[dt] = __builtin_amdgcn_mfma_f32_16x16x32_bf16(pa0, vb0, oacc[dt], 0, 0, 0);
            oacc[dt] = __builtin_amdgcn_mfma_f32_16x16x32_bf16(pa1, vb1, oacc[dt], 0, 0, 0);
        }
    }
#pragma unroll
    for (int off = 1; off < 16; off <<= 1)
#pragma unroll
        for (int r = 0; r < 4; ++r) sum[r] += __shfl_xor(sum[r], off);
    float inv[4];
#pragma unroll
    for (int r = 0; r < 4; ++r) inv[r] = 1.0f / sum[r];

#pragma unroll
    for (int dt = 0; dt < 2; ++dt)
#pragma unroll
        for (int r = 0; r < 4; ++r)
            ob[(rowbase + q0 + lk*4 + r)*256 + h*32 + dt*16 + lm] = f2bf(oacc[dt][r] * inv[r]);
}

// ---------------------------------------------------------------------------
extern "C" void kernel_launch(void* const* d_in, const int* in_sizes, int n_in,
                              void* d_out, int out_size, void* d_ws, size_t ws_size,
                              hipStream_t stream)
{
    const float* x_in = (const float*)d_in[0];
    const unsigned char* mask = (const unsigned char*)d_in[1];
    const float* pe   = (const float*)d_in[2];
    const float* Wq = (const float*)d_in[3];
    const float* bq = (const float*)d_in[4];
    const float* Wk = (const float*)d_in[5];
    const float* bk = (const float*)d_in[6];
    const float* Wv = (const float*)d_in[7];
    const float* bv = (const float*)d_in[8];
    const float* Wo = (const float*)d_in[9];
    const float* bo = (const float*)d_in[10];
    const float* W1 = (const float*)d_in[11];
    const float* bf1 = (const float*)d_in[12];
    const float* W2 = (const float*)d_in[13];
    const float* bf2 = (const float*)d_in[14];
    const float* ln1_g = (const float*)d_in[15];
    const float* ln1_b = (const float*)d_in[16];
    const float* ln2_g = (const float*)d_in[17];
    const float* ln2_b = (const float*)d_in[18];

    float* x = (float*)d_out;                 // fp32 residual stream [M,256]
    u16* ws = (u16*)d_ws;
    u16* qkv  = ws;                           //  [M,768] bf16 (Q pre-scaled; V region unused)
    u16* ob   = qkv + 11010048;               //  [M,256] bf16
    u16* vtg  = ob + 3670016;                 //  [b,h,32,448] bf16
    u16* hb   = qkv;                          //  [M,1024] bf16 (aliases qkv+ob)
    u16* wqkvt = vtg + 3670016;               //  [12][768][256]
    u16* wot  = wqkvt + 2359296;              //  [12][256][256]
    u16* w1t  = wot + 786432;                 //  [12][1024][256]
    u16* w2t  = w1t + 3145728;                //  [12][256][1024]
    float* bqkv = (float*)(w2t + 3145728);    //  [12][768]

    add_pos_k<<<MTOK * DM / 1024, 256, 0, stream>>>(x_in, pe, x);

    twt_k<<<dim3(8, 8, NL), 256, 0, stream>>>(Wq, wqkvt,          256, 256, 65536, 196608);
    twt_k<<<dim3(8, 8, NL), 256, 0, stream>>>(Wk, wqkvt + 65536,  256, 256, 65536, 196608);
    twt_k<<<dim3(8, 8, NL), 256, 0, stream>>>(Wv, wqkvt + 131072, 256, 256, 65536, 196608);
    twt_k<<<dim3(8, 8, NL), 256, 0, stream>>>(Wo, wot, 256, 256, 65536, 65536);
    twt_k<<<dim3(32, 8, NL), 256, 0, stream>>>(W1, w1t, 256, 1024, 262144, 262144);
    twt_k<<<dim3(8, 32, NL), 256, 0, stream>>>(W2, w2t, 1024, 256, 262144, 262144);
    pack_bias_k<<<(NL * 768 + 255) / 256, 256, 0, stream>>>(bq, bk, bv, bqkv);

    for (int l = 0; l < NL; ++l) {
        mmln_k<0><<<dim3(112, 12), 256, 0, stream>>>(
            x, ln1_g + l*256, ln1_b + l*256, wqkvt + (size_t)l*196608,
            bqkv + l*768, qkv, 768, vtg);
        attn_k<<<1792, 256, 0, stream>>>(qkv, vtg, mask, ob);
        mm_k<2><<<dim3(112, 4), 256, 0, stream>>>(
            ob, 256, wot + (size_t)l*65536, bo + l*256, x, 256, 256);
        mmln_k<1><<<dim3(112, 16), 256, 0, stream>>>(
            x, ln2_g + l*256, ln2_b + l*256, w1t + (size_t)l*262144,
            bf1 + l*1024, hb, 1024, nullptr);
        mm_k<2><<<dim3(112, 4), 256, 0, stream>>>(
            hb, 1024, w2t + (size_t)l*262144, bf2 + l*256, x, 256, 1024);
    }
}

// Round 9
// 1540.794 us; speedup vs baseline: 1.9332x; 1.9332x over previous
//
#include <hip/hip_runtime.h>

#define NL 12
#define DM 256
#define FFDIM 1024
#define BBATCH 32
#define LSEQ 448
#define MTOK (BBATCH*LSEQ)     // 14336
#define EPSF 1e-6f
// 1/sqrt(32) * log2(e): Q pre-scale so attn can use exp2 directly
#define QSCALE_LOG2E (0.17677669529663687f * 1.4426950408889634f)

typedef __attribute__((ext_vector_type(8))) short bf16x8;
typedef __attribute__((ext_vector_type(4))) float f32x4;
typedef unsigned short u16;
typedef unsigned int u32;

__device__ __forceinline__ u16 f2bf(float f) {
    union { float f; u32 u; } v; v.f = f;
    u32 r = v.u + 0x7fffu + ((v.u >> 16) & 1u);
    return (u16)(r >> 16);
}
__device__ __forceinline__ float gelu_exact(float x) {
    return 0.5f * x * (1.0f + erff(x * 0.70710678118654752f));
}
__device__ __forceinline__ void gload16(const u16* g, u16* l) {
    __builtin_amdgcn_global_load_lds(
        (const __attribute__((address_space(1))) u32*)g,
        (__attribute__((address_space(3))) u32*)l, 16, 0, 0);
}

// ---------------------------------------------------------------------------
__global__ __launch_bounds__(256) void add_pos_k(
    const float* __restrict__ x, const float* __restrict__ pe, float* __restrict__ out)
{
    int i = blockIdx.x * 256 + threadIdx.x;
    float4 xv = ((const float4*)x)[i];
    float4 pv = ((const float4*)pe)[i % (LSEQ * DM / 4)];
    float4 r;
    r.x = xv.x + pv.x; r.y = xv.y + pv.y; r.z = xv.z + pv.z; r.w = xv.w + pv.w;
    ((float4*)out)[i] = r;
}

// ---------------------------------------------------------------------------
__global__ __launch_bounds__(256) void ln_k(
    const float* __restrict__ x, const float* __restrict__ g,
    const float* __restrict__ b, u16* __restrict__ out)
{
    const int w = threadIdx.x >> 6, lane = threadIdx.x & 63;
    const int row = blockIdx.x * 4 + w;
    float4 v = ((const float4*)(x + (size_t)row * DM))[lane];
    float s = v.x + v.y + v.z + v.w;
#pragma unroll
    for (int off = 32; off; off >>= 1) s += __shfl_xor(s, off);
    float mu = s * (1.0f / 256.0f);
    float d0 = v.x - mu, d1 = v.y - mu, d2 = v.z - mu, d3 = v.w - mu;
    float sq = d0*d0 + d1*d1 + d2*d2 + d3*d3;
#pragma unroll
    for (int off = 32; off; off >>= 1) sq += __shfl_xor(sq, off);
    float rs = rsqrtf(sq * (1.0f / 256.0f) + EPSF);
    float4 gv = ((const float4*)g)[lane];
    float4 bv = ((const float4*)b)[lane];
    ushort4 o;
    o.x = f2bf(d0 * rs * gv.x + bv.x);
    o.y = f2bf(d1 * rs * gv.y + bv.y);
    o.z = f2bf(d2 * rs * gv.z + bv.z);
    o.w = f2bf(d3 * rs * gv.w + bv.w);
    *(ushort4*)(out + (size_t)row * DM + lane * 4) = o;
}

// ---------------------------------------------------------------------------
// Weight transpose + cvt: fp32 [layer][K][N] -> bf16 [layer][N][K]
__global__ __launch_bounds__(256) void twt_k(
    const float* __restrict__ in, u16* __restrict__ out,
    int K, int N, int in_lstride, int out_lstride)
{
    __shared__ float tl[32][33];
    const int l = blockIdx.z;
    const int n0 = blockIdx.x * 32, k0 = blockIdx.y * 32;
    const int tx = threadIdx.x & 31, ty = threadIdx.x >> 5;
    const float* src = in + (size_t)l * in_lstride;
#pragma unroll
    for (int i = 0; i < 4; ++i)
        tl[ty + 8*i][tx] = src[(size_t)(k0 + ty + 8*i) * N + n0 + tx];
    __syncthreads();
    u16* dst = out + (size_t)l * out_lstride;
#pragma unroll
    for (int i = 0; i < 4; ++i)
        dst[(size_t)(n0 + ty + 8*i) * K + k0 + tx] = f2bf(tl[tx][ty + 8*i]);
}

__global__ __launch_bounds__(256) void pack_bias_k(
    const float* __restrict__ bq, const float* __restrict__ bk,
    const float* __restrict__ bv, float* __restrict__ bqkv)
{
    int i = blockIdx.x * 256 + threadIdx.x;
    if (i >= NL * 768) return;
    int l = i / 768, c = i % 768;
    float v = (c < 256) ? bq[l*256 + c] : (c < 512) ? bk[l*256 + c - 256] : bv[l*256 + c - 512];
    bqkv[i] = v;
}

// ---------------------------------------------------------------------------
// bf16 MFMA GEMM, double-buffered single-barrier K-loop (loads overlap compute):
//   stage(buf0,k=0); for it: { barrier; stage(buf^1,k+1); compute(buf); }
// C = A[M,K] @ Bt[N,K]^T + bias. BM=128, BK=32, BN in {64,128}.
// Wave partition: BN=128: 2x2 waves of 64x64 (MT=4); BN=64: 4 waves of 32x64 (MT=2).
// Grid (Mblocks=112, Nblocks): M-major => same-A blocks share an XCD.
// EPI: 1 gelu->bf16, 2 fp32 residual +=,
//      3 QKV: cols<256 Q*QSCALE_LOG2E -> C; 256..511 K -> C;
//             512..767 V packed ushort4 -> vtg[b][h][d][s]
template<int BN, int EPI>
__global__ __launch_bounds__(256, (BN == 64) ? 4 : 3) void mm_k(
    const u16* __restrict__ A, int lda, const u16* __restrict__ Bt,
    const float* __restrict__ bias, void* __restrict__ C, int ldc, int K,
    u16* __restrict__ vtg)
{
    __shared__ u16 As[2][128 * 32];
    __shared__ u16 Bs[2][BN * 32];
    constexpr int MT = BN / 32;               // 4 for BN=128, 2 for BN=64
    const int tid = threadIdx.x;
    const int by = blockIdx.x, bx = blockIdx.y;   // by = M-block (XCD pin)
    const int w = tid >> 6, lane = tid & 63;
    const int lm = lane & 15, lk = lane >> 4;
    const int m0 = (BN == 128) ? ((w >> 1) * 64) : (w * 32);
    const int n0 = (BN == 128) ? ((w & 1) * 64) : 0;
    const int lrow = lane >> 2, lcol = (lane & 3) * 8;

    const u16* Ab = A + (size_t)(by * 128) * lda;
    const u16* Bb = Bt + (size_t)(bx * BN) * K;

    f32x4 zz = {0.f, 0.f, 0.f, 0.f};
    f32x4 acc[MT][4];
#pragma unroll
    for (int i = 0; i < MT; ++i)
#pragma unroll
        for (int j = 0; j < 4; ++j) acc[i][j] = zz;

    auto stage = [&](int buf, int k0) {
#pragma unroll
        for (int i = 0; i < 2; ++i) {
            int seg = w * 2 + i;
            gload16(Ab + (size_t)(seg * 16 + lrow) * lda + k0 + lcol, &As[buf][seg * 512]);
        }
        if constexpr (BN == 128) {
#pragma unroll
            for (int i = 0; i < 2; ++i) {
                int seg = w * 2 + i;
                gload16(Bb + (size_t)(seg * 16 + lrow) * K + k0 + lcol, &Bs[buf][seg * 512]);
            }
        } else {
            gload16(Bb + (size_t)(w * 16 + lrow) * K + k0 + lcol, &Bs[buf][w * 512]);
        }
    };

    stage(0, 0);
    const int NK = K >> 5;
    for (int it = 0; it < NK; ++it) {
        const int cur = it & 1;
        __syncthreads();                       // drains loads for iter `it`
        if (it + 1 < NK) stage(1 - cur, (it + 1) * 32);   // in flight during compute
        bf16x8 af[MT], bfr[4];
#pragma unroll
        for (int mt = 0; mt < MT; ++mt)
            af[mt] = *(const bf16x8*)&As[cur][(m0 + mt*16 + lm)*32 + lk*8];
#pragma unroll
        for (int nt = 0; nt < 4; ++nt)
            bfr[nt] = *(const bf16x8*)&Bs[cur][(n0 + nt*16 + lm)*32 + lk*8];
#pragma unroll
        for (int mt = 0; mt < MT; ++mt)
#pragma unroll
            for (int nt = 0; nt < 4; ++nt)
                acc[mt][nt] = __builtin_amdgcn_mfma_f32_16x16x32_bf16(af[mt], bfr[nt], acc[mt][nt], 0, 0, 0);
    }

    float bv[4];
#pragma unroll
    for (int nt = 0; nt < 4; ++nt) bv[nt] = bias[bx*BN + n0 + nt*16 + lm];
#pragma unroll
    for (int mt = 0; mt < MT; ++mt) {
        int grow0 = by*128 + m0 + mt*16 + lk*4;
#pragma unroll
        for (int nt = 0; nt < 4; ++nt) {
            int gcol = bx*BN + n0 + nt*16 + lm;
            float v0 = acc[mt][nt][0] + bv[nt];
            float v1 = acc[mt][nt][1] + bv[nt];
            float v2 = acc[mt][nt][2] + bv[nt];
            float v3 = acc[mt][nt][3] + bv[nt];
            if constexpr (EPI == 1) {
                u16* cp = (u16*)C + (size_t)grow0 * ldc + gcol;
                cp[0]            = f2bf(gelu_exact(v0));
                cp[ldc]          = f2bf(gelu_exact(v1));
                cp[2*(size_t)ldc] = f2bf(gelu_exact(v2));
                cp[3*(size_t)ldc] = f2bf(gelu_exact(v3));
            } else if constexpr (EPI == 3) {
                if (gcol < 512) {
                    float qs = (gcol < 256) ? QSCALE_LOG2E : 1.0f;
                    u16* cp = (u16*)C + (size_t)grow0 * ldc + gcol;
                    cp[0]            = f2bf(v0 * qs);
                    cp[ldc]          = f2bf(v1 * qs);
                    cp[2*(size_t)ldc] = f2bf(v2 * qs);
                    cp[3*(size_t)ldc] = f2bf(v3 * qs);
                } else {
                    int c = gcol - 512;
                    int hh = c >> 5, d = c & 31;
                    u32 bidx = (u32)grow0 / 448u;
                    int srow = grow0 - (int)bidx * 448;   // 4-aligned (448%4==0)
                    ushort4 st;
                    st.x = f2bf(v0); st.y = f2bf(v1); st.z = f2bf(v2); st.w = f2bf(v3);
                    *(ushort4*)&vtg[((size_t)(bidx*8 + hh)*32 + d)*448 + srow] = st;
                }
            } else {
                float* p = (float*)C + (size_t)grow0 * ldc + gcol;
                p[0]   += v0;
                p[ldc] += v1;
                p[2*(size_t)ldc] += v2;
                p[3*(size_t)ldc] += v3;
            }
        }
    }
}

// ---------------------------------------------------------------------------
// MFMA attention, single-pass, no max subtraction (scores O(0.1); softmax is
// shift-invariant; masked keys -> p = 0 exactly). Q pre-scaled by
// 1/sqrt(dk)*log2(e) -> exp2f. Grid bid = sg*256 + bh (XCD pin).
__global__ __launch_bounds__(256, 4) void attn_k(
    const u16* __restrict__ qkv, const u16* __restrict__ vtg,
    const unsigned char* __restrict__ mask, u16* __restrict__ ob)
{
    __shared__ u16 Klds[448 * 32];
    __shared__ u16 Plds[4][16 * 68];
    const int tid = threadIdx.x, w = tid >> 6, lane = tid & 63;
    const int lm = lane & 15, lk = lane >> 4;
    const int bid = blockIdx.x;
    const int bh = bid & 255, sg = bid >> 8;
    const int b = bh >> 3, h = bh & 7;
    const size_t rowbase = (size_t)b * LSEQ;

#pragma unroll
    for (int i = 0; i < 7; ++i) {
        int seg = w * 7 + i;
        gload16(qkv + (rowbase + seg * 16 + (lane >> 2)) * 768 + 256 + h * 32 + (lane & 3) * 8,
                &Klds[seg * 512]);
    }
    unsigned mbits = 0;
#pragma unroll
    for (int t = 0; t < 28; ++t)
        mbits |= (mask[b * LSEQ + t * 16 + lm] ? 1u : 0u) << t;
    __syncthreads();

    const u16* Vb = vtg + (size_t)bh * 32 * 448;
    f32x4 zz = {0.f, 0.f, 0.f, 0.f};

    const int q0 = (sg * 4 + w) * 16;
    bf16x8 qf = *(const bf16x8*)(qkv + (rowbase + q0 + lm) * 768 + h * 32 + lk * 8);

    f32x4 oacc[2] = {zz, zz};
    float sum[4] = {0.f, 0.f, 0.f, 0.f};
    u16* P = &Plds[w][0];
#pragma unroll
    for (int cc = 0; cc < 7; ++cc) {
#pragma unroll
        for (int tt = 0; tt < 4; ++tt) {
            int t = cc*4 + tt;
            bf16x8 kf = *(const bf16x8*)&Klds[(t*16 + lm)*32 + lk*8];
            f32x4 s = __builtin_amdgcn_mfma_f32_16x16x32_bf16(qf, kf, zz, 0, 0, 0);
            bool m = (mbits >> t) & 1;
#pragma unroll
            for (int r = 0; r < 4; ++r) {
                float e = m ? 0.f : exp2f(s[r]);
                sum[r] += e;
                P[(lk*4 + r)*68 + tt*16 + lm] = f2bf(e);
            }
        }
        bf16x8 pa0 = *(const bf16x8*)&P[lm*68 + lk*8];
        bf16x8 pa1 = *(const bf16x8*)&P[lm*68 + 32 + lk*8];
#pragma unroll
        for (int dt = 0; dt < 2; ++dt) {
            bf16x8 vb0 = *(const bf16x8*)(Vb + (size_t)(dt*16 + lm)*448 + cc*64 + lk*8);
            bf16x8 vb1 = *(const bf16x8*)(Vb + (size_t)(dt*16 + lm)*448 + cc*64 + 32 + lk*8);
            oacc[dt] = __builtin_amdgcn_mfma_f32_16x16x32_bf16(pa0, vb0, oacc[dt], 0, 0, 0);
            oacc[dt] = __builtin_amdgcn_mfma_f32_16x16x32_bf16(pa1, vb1, oacc[dt], 0, 0, 0);
        }
    }
#pragma unroll
    for (int off = 1; off < 16; off <<= 1)
#pragma unroll
        for (int r = 0; r < 4; ++r) sum[r] += __shfl_xor(sum[r], off);
    float inv[4];
#pragma unroll
    for (int r = 0; r < 4; ++r) inv[r] = 1.0f / sum[r];

#pragma unroll
    for (int dt = 0; dt < 2; ++dt)
#pragma unroll
        for (int r = 0; r < 4; ++r)
            ob[(rowbase + q0 + lk*4 + r)*256 + h*32 + dt*16 + lm] = f2bf(oacc[dt][r] * inv[r]);
}

// ---------------------------------------------------------------------------
extern "C" void kernel_launch(void* const* d_in, const int* in_sizes, int n_in,
                              void* d_out, int out_size, void* d_ws, size_t ws_size,
                              hipStream_t stream)
{
    const float* x_in = (const float*)d_in[0];
    const unsigned char* mask = (const unsigned char*)d_in[1];
    const float* pe   = (const float*)d_in[2];
    const float* Wq = (const float*)d_in[3];
    const float* bq = (const float*)d_in[4];
    const float* Wk = (const float*)d_in[5];
    const float* bk = (const float*)d_in[6];
    const float* Wv = (const float*)d_in[7];
    const float* bv = (const float*)d_in[8];
    const float* Wo = (const float*)d_in[9];
    const float* bo = (const float*)d_in[10];
    const float* W1 = (const float*)d_in[11];
    const float* bf1 = (const float*)d_in[12];
    const float* W2 = (const float*)d_in[13];
    const float* bf2 = (const float*)d_in[14];
    const float* ln1_g = (const float*)d_in[15];
    const float* ln1_b = (const float*)d_in[16];
    const float* ln2_g = (const float*)d_in[17];
    const float* ln2_b = (const float*)d_in[18];

    float* x = (float*)d_out;                 // fp32 residual stream [M,256]
    u16* ws = (u16*)d_ws;
    u16* nx   = ws;                           //  [M,256] bf16
    u16* qkv  = nx + 3670016;                 //  [M,768] bf16 (Q pre-scaled; V cols -> vtg)
    u16* ob   = qkv + 11010048;               //  [M,256] bf16
    u16* vtg  = ob + 3670016;                 //  [b,h,32,448] bf16
    u16* hb   = qkv;                          //  [M,1024] bf16 (aliases qkv+ob)
    u16* wqkvt = vtg + 3670016;               //  [12][768][256]
    u16* wot  = wqkvt + 2359296;              //  [12][256][256]
    u16* w1t  = wot + 786432;                 //  [12][1024][256]
    u16* w2t  = w1t + 3145728;                //  [12][256][1024]
    float* bqkv = (float*)(w2t + 3145728);    //  [12][768]

    add_pos_k<<<MTOK * DM / 1024, 256, 0, stream>>>(x_in, pe, x);

    twt_k<<<dim3(8, 8, NL), 256, 0, stream>>>(Wq, wqkvt,          256, 256, 65536, 196608);
    twt_k<<<dim3(8, 8, NL), 256, 0, stream>>>(Wk, wqkvt + 65536,  256, 256, 65536, 196608);
    twt_k<<<dim3(8, 8, NL), 256, 0, stream>>>(Wv, wqkvt + 131072, 256, 256, 65536, 196608);
    twt_k<<<dim3(8, 8, NL), 256, 0, stream>>>(Wo, wot, 256, 256, 65536, 65536);
    twt_k<<<dim3(32, 8, NL), 256, 0, stream>>>(W1, w1t, 256, 1024, 262144, 262144);
    twt_k<<<dim3(8, 32, NL), 256, 0, stream>>>(W2, w2t, 1024, 256, 262144, 262144);
    pack_bias_k<<<(NL * 768 + 255) / 256, 256, 0, stream>>>(bq, bk, bv, bqkv);

    for (int l = 0; l < NL; ++l) {
        ln_k<<<MTOK / 4, 256, 0, stream>>>(x, ln1_g + l*256, ln1_b + l*256, nx);
        mm_k<128, 3><<<dim3(112, 6), 256, 0, stream>>>(
            nx, 256, wqkvt + (size_t)l*196608, bqkv + l*768, qkv, 768, 256, vtg);
        attn_k<<<1792, 256, 0, stream>>>(qkv, vtg, mask, ob);
        mm_k<64, 2><<<dim3(112, 4), 256, 0, stream>>>(
            ob, 256, wot + (size_t)l*65536, bo + l*256, x, 256, 256, nullptr);
        ln_k<<<MTOK / 4, 256, 0, stream>>>(x, ln2_g + l*256, ln2_b + l*256, nx);
        mm_k<128, 1><<<dim3(112, 8), 256, 0, stream>>>(
            nx, 256, w1t + (size_t)l*262144, bf1 + l*1024, hb, 1024, 256, nullptr);
        mm_k<64, 2><<<dim3(112, 4), 256, 0, stream>>>(
            hb, 1024, w2t + (size_t)l*262144, bf2 + l*256, x, 256, 1024, nullptr);
    }
}

// Round 10
// 1456.486 us; speedup vs baseline: 2.0451x; 1.0579x over previous
//
#include <hip/hip_runtime.h>

#define NL 12
#define DM 256
#define FFDIM 1024
#define BBATCH 32
#define LSEQ 448
#define MTOK (BBATCH*LSEQ)     // 14336
#define EPSF 1e-6f
// 1/sqrt(32) * log2(e): Q pre-scale so attn can use exp2 directly
#define QSCALE_LOG2E (0.17677669529663687f * 1.4426950408889634f)

typedef __attribute__((ext_vector_type(8))) short bf16x8;
typedef __attribute__((ext_vector_type(4))) float f32x4;
typedef unsigned short u16;
typedef unsigned int u32;

__device__ __forceinline__ u16 f2bf(float f) {
    union { float f; u32 u; } v; v.f = f;
    u32 r = v.u + 0x7fffu + ((v.u >> 16) & 1u);
    return (u16)(r >> 16);
}
__device__ __forceinline__ float gelu_exact(float x) {
    return 0.5f * x * (1.0f + erff(x * 0.70710678118654752f));
}
__device__ __forceinline__ void gload16(const u16* g, u16* l) {
    __builtin_amdgcn_global_load_lds(
        (const __attribute__((address_space(1))) u32*)g,
        (__attribute__((address_space(3))) u32*)l, 16, 0, 0);
}

// ---------------------------------------------------------------------------
// x = x_in + pos_emb, then LN1(layer 0): wave per row, writes x fp32 + nx bf16
__global__ __launch_bounds__(256) void ln0_k(
    const float* __restrict__ xin, const float* __restrict__ pe,
    const float* __restrict__ g, const float* __restrict__ b,
    float* __restrict__ x, u16* __restrict__ nx)
{
    const int w = threadIdx.x >> 6, lane = threadIdx.x & 63;
    const int row = blockIdx.x * 4 + w;
    const int prow = row % LSEQ;
    float4 v = ((const float4*)(xin + (size_t)row * DM))[lane];
    float4 p = ((const float4*)(pe + (size_t)prow * DM))[lane];
    v.x += p.x; v.y += p.y; v.z += p.z; v.w += p.w;
    ((float4*)(x + (size_t)row * DM))[lane] = v;
    float s = v.x + v.y + v.z + v.w;
#pragma unroll
    for (int off = 32; off; off >>= 1) s += __shfl_xor(s, off);
    float mu = s * (1.0f / 256.0f);
    float d0 = v.x - mu, d1 = v.y - mu, d2 = v.z - mu, d3 = v.w - mu;
    float sq = d0*d0 + d1*d1 + d2*d2 + d3*d3;
#pragma unroll
    for (int off = 32; off; off >>= 1) sq += __shfl_xor(sq, off);
    float rs = rsqrtf(sq * (1.0f / 256.0f) + EPSF);
    float4 gv = ((const float4*)g)[lane];
    float4 bv = ((const float4*)b)[lane];
    ushort4 o;
    o.x = f2bf(d0 * rs * gv.x + bv.x);
    o.y = f2bf(d1 * rs * gv.y + bv.y);
    o.z = f2bf(d2 * rs * gv.z + bv.z);
    o.w = f2bf(d3 * rs * gv.w + bv.w);
    *(ushort4*)(nx + (size_t)row * DM + lane * 4) = o;
}

// ---------------------------------------------------------------------------
// Weight transpose + cvt: fp32 [layer][K][N] -> bf16 [layer][N][K]
__global__ __launch_bounds__(256) void twt_k(
    const float* __restrict__ in, u16* __restrict__ out,
    int K, int N, int in_lstride, int out_lstride)
{
    __shared__ float tl[32][33];
    const int l = blockIdx.z;
    const int n0 = blockIdx.x * 32, k0 = blockIdx.y * 32;
    const int tx = threadIdx.x & 31, ty = threadIdx.x >> 5;
    const float* src = in + (size_t)l * in_lstride;
#pragma unroll
    for (int i = 0; i < 4; ++i)
        tl[ty + 8*i][tx] = src[(size_t)(k0 + ty + 8*i) * N + n0 + tx];
    __syncthreads();
    u16* dst = out + (size_t)l * out_lstride;
#pragma unroll
    for (int i = 0; i < 4; ++i)
        dst[(size_t)(n0 + ty + 8*i) * K + k0 + tx] = f2bf(tl[tx][ty + 8*i]);
}

__global__ __launch_bounds__(256) void pack_bias_k(
    const float* __restrict__ bq, const float* __restrict__ bk,
    const float* __restrict__ bv, float* __restrict__ bqkv)
{
    int i = blockIdx.x * 256 + threadIdx.x;
    if (i >= NL * 768) return;
    int l = i / 768, c = i % 768;
    float v = (c < 256) ? bq[l*256 + c] : (c < 512) ? bk[l*256 + c - 256] : bv[l*256 + c - 512];
    bqkv[i] = v;
}

// ---------------------------------------------------------------------------
// bf16 MFMA GEMM (R7 2-barrier BK=64): C = A[M,K] @ Bt[N,K]^T + bias.
// BM=128, BN=128, 2x2 waves of 64x64 (MT=4). Grid (Mblocks=112, Nblocks).
// EPI: 1 gelu->bf16 (FF1), 3 QKV (Q*QSCALE_LOG2E, K, V packed -> vtg)
template<int EPI>
__global__ __launch_bounds__(256, 3) void mm_k(
    const u16* __restrict__ A, int lda, const u16* __restrict__ Bt,
    const float* __restrict__ bias, u16* __restrict__ C, int ldc, int K,
    u16* __restrict__ vtg)
{
    __shared__ u16 As[2][128 * 32];
    __shared__ u16 Bs[2][128 * 32];
    const int tid = threadIdx.x;
    const int by = blockIdx.x, bx = blockIdx.y;
    const int w = tid >> 6, lane = tid & 63;
    const int lm = lane & 15, lk = lane >> 4;
    const int m0 = (w >> 1) * 64, n0 = (w & 1) * 64;
    const int lrow = lane >> 2, lcol = (lane & 3) * 8;

    const u16* Ab = A + (size_t)(by * 128) * lda;
    const u16* Bb = Bt + (size_t)(bx * 128) * K;

    f32x4 zz = {0.f, 0.f, 0.f, 0.f};
    f32x4 acc[4][4];
#pragma unroll
    for (int i = 0; i < 4; ++i)
#pragma unroll
        for (int j = 0; j < 4; ++j) acc[i][j] = zz;

    for (int k0 = 0; k0 < K; k0 += 64) {
        __syncthreads();
#pragma unroll
        for (int p = 0; p < 2; ++p)
#pragma unroll
            for (int i = 0; i < 2; ++i) {
                int seg = w * 2 + i;
                gload16(Ab + (size_t)(seg * 16 + lrow) * lda + k0 + p * 32 + lcol,
                        &As[p][seg * 512]);
                gload16(Bb + (size_t)(seg * 16 + lrow) * K + k0 + p * 32 + lcol,
                        &Bs[p][seg * 512]);
            }
        __syncthreads();
#pragma unroll
        for (int p = 0; p < 2; ++p) {
            bf16x8 af[4], bfr[4];
#pragma unroll
            for (int mt = 0; mt < 4; ++mt)
                af[mt] = *(const bf16x8*)&As[p][(m0 + mt*16 + lm)*32 + lk*8];
#pragma unroll
            for (int nt = 0; nt < 4; ++nt)
                bfr[nt] = *(const bf16x8*)&Bs[p][(n0 + nt*16 + lm)*32 + lk*8];
#pragma unroll
            for (int mt = 0; mt < 4; ++mt)
#pragma unroll
                for (int nt = 0; nt < 4; ++nt)
                    acc[mt][nt] = __builtin_amdgcn_mfma_f32_16x16x32_bf16(af[mt], bfr[nt], acc[mt][nt], 0, 0, 0);
        }
    }

    float bv[4];
#pragma unroll
    for (int nt = 0; nt < 4; ++nt) bv[nt] = bias[bx*128 + n0 + nt*16 + lm];
#pragma unroll
    for (int mt = 0; mt < 4; ++mt) {
        int grow0 = by*128 + m0 + mt*16 + lk*4;
#pragma unroll
        for (int nt = 0; nt < 4; ++nt) {
            int gcol = bx*128 + n0 + nt*16 + lm;
            float v0 = acc[mt][nt][0] + bv[nt];
            float v1 = acc[mt][nt][1] + bv[nt];
            float v2 = acc[mt][nt][2] + bv[nt];
            float v3 = acc[mt][nt][3] + bv[nt];
            if constexpr (EPI == 1) {
                u16* cp = C + (size_t)grow0 * ldc + gcol;
                cp[0]             = f2bf(gelu_exact(v0));
                cp[ldc]           = f2bf(gelu_exact(v1));
                cp[2*(size_t)ldc] = f2bf(gelu_exact(v2));
                cp[3*(size_t)ldc] = f2bf(gelu_exact(v3));
            } else {
                if (gcol < 512) {
                    float qs = (gcol < 256) ? QSCALE_LOG2E : 1.0f;
                    u16* cp = C + (size_t)grow0 * ldc + gcol;
                    cp[0]             = f2bf(v0 * qs);
                    cp[ldc]           = f2bf(v1 * qs);
                    cp[2*(size_t)ldc] = f2bf(v2 * qs);
                    cp[3*(size_t)ldc] = f2bf(v3 * qs);
                } else {
                    int c = gcol - 512;
                    int hh = c >> 5, d = c & 31;
                    u32 bidx = (u32)grow0 / 448u;
                    int srow = grow0 - (int)bidx * 448;   // 4-aligned, no boundary cross
                    ushort4 st;
                    st.x = f2bf(v0); st.y = f2bf(v1); st.z = f2bf(v2); st.w = f2bf(v3);
                    *(ushort4*)&vtg[((size_t)(bidx*8 + hh)*32 + d)*448 + srow] = st;
                }
            }
        }
    }
}

// ---------------------------------------------------------------------------
// Full-row GEMM (N=256) + residual + optional fused LayerNorm:
//   X[row] += A@Bt^T + bias;  if DOLN: nx[row] = LN(X[row]) in bf16.
// BM=64, BN=256: 4 waves, each 16 rows x 256 cols (NT=16, acc=64 f32).
// Row reduce: in-lane over nt, then shfl_xor 1/2/4/8 across the 16-lane group.
template<bool DOLN>
__global__ __launch_bounds__(256, 3) void mmrow_k(
    const u16* __restrict__ A, int lda, const u16* __restrict__ Bt,
    const float* __restrict__ bias, float* __restrict__ X,
    const float* __restrict__ g, const float* __restrict__ b,
    u16* __restrict__ nx, int K)
{
    __shared__ u16 As[2][64 * 32];
    __shared__ u16 Bs[2][256 * 32];
    const int tid = threadIdx.x, by = blockIdx.x;
    const int w = tid >> 6, lane = tid & 63;
    const int lm = lane & 15, lk = lane >> 4;
    const int m0 = w * 16;
    const int lrow = lane >> 2, lcol = (lane & 3) * 8;

    const u16* Ab = A + (size_t)(by * 64) * lda;

    f32x4 zz = {0.f, 0.f, 0.f, 0.f};
    f32x4 acc[16];
#pragma unroll
    for (int i = 0; i < 16; ++i) acc[i] = zz;

    for (int k0 = 0; k0 < K; k0 += 64) {
        __syncthreads();
#pragma unroll
        for (int p = 0; p < 2; ++p) {
            gload16(Ab + (size_t)(w * 16 + lrow) * lda + k0 + p * 32 + lcol,
                    &As[p][w * 512]);
#pragma unroll
            for (int i = 0; i < 4; ++i) {
                int seg = w * 4 + i;
                gload16(Bt + (size_t)(seg * 16 + lrow) * K + k0 + p * 32 + lcol,
                        &Bs[p][seg * 512]);
            }
        }
        __syncthreads();
#pragma unroll
        for (int p = 0; p < 2; ++p) {
            bf16x8 af = *(const bf16x8*)&As[p][(m0 + lm)*32 + lk*8];
#pragma unroll
            for (int nt = 0; nt < 16; ++nt) {
                bf16x8 bfr = *(const bf16x8*)&Bs[p][(nt*16 + lm)*32 + lk*8];
                acc[nt] = __builtin_amdgcn_mfma_f32_16x16x32_bf16(af, bfr, acc[nt], 0, 0, 0);
            }
        }
    }

    const int row0 = by*64 + m0 + lk*4;
    float sum[4] = {0.f, 0.f, 0.f, 0.f};
#pragma unroll
    for (int nt = 0; nt < 16; ++nt) {
        float bvv = bias[nt*16 + lm];
        const float* xp = X + (size_t)row0 * 256 + nt*16 + lm;
#pragma unroll
        for (int r = 0; r < 4; ++r) {
            float xn = xp[(size_t)r * 256] + acc[nt][r] + bvv;
            acc[nt][r] = xn;
            sum[r] += xn;
        }
    }
    if constexpr (DOLN) {
#pragma unroll
        for (int off = 1; off < 16; off <<= 1)
#pragma unroll
            for (int r = 0; r < 4; ++r) sum[r] += __shfl_xor(sum[r], off);
        float mu[4], sq[4] = {0.f, 0.f, 0.f, 0.f};
#pragma unroll
        for (int r = 0; r < 4; ++r) mu[r] = sum[r] * (1.0f / 256.0f);
#pragma unroll
        for (int nt = 0; nt < 16; ++nt)
#pragma unroll
            for (int r = 0; r < 4; ++r) {
                float d = acc[nt][r] - mu[r];
                sq[r] += d * d;
            }
#pragma unroll
        for (int off = 1; off < 16; off <<= 1)
#pragma unroll
            for (int r = 0; r < 4; ++r) sq[r] += __shfl_xor(sq[r], off);
        float rs[4];
#pragma unroll
        for (int r = 0; r < 4; ++r) rs[r] = rsqrtf(sq[r] * (1.0f / 256.0f) + EPSF);
#pragma unroll
        for (int nt = 0; nt < 16; ++nt) {
            int col = nt*16 + lm;
            float gc = g[col], bc = b[col];
            float* xp = X + (size_t)row0 * 256 + col;
            u16* np = nx + (size_t)row0 * 256 + col;
#pragma unroll
            for (int r = 0; r < 4; ++r) {
                xp[(size_t)r * 256] = acc[nt][r];
                np[(size_t)r * 256] = f2bf((acc[nt][r] - mu[r]) * rs[r] * gc + bc);
            }
        }
    } else {
#pragma unroll
        for (int nt = 0; nt < 16; ++nt) {
            float* xp = X + (size_t)row0 * 256 + nt*16 + lm;
#pragma unroll
            for (int r = 0; r < 4; ++r) xp[(size_t)r * 256] = acc[nt][r];
        }
    }
}

// ---------------------------------------------------------------------------
// MFMA attention, single-pass, no max subtraction (scores O(0.1); softmax is
// shift-invariant; masked keys -> p = 0 exactly). Q pre-scaled by
// 1/sqrt(dk)*log2(e) -> exp2f. Grid bid = sg*256 + bh (XCD pin).
__global__ __launch_bounds__(256, 4) void attn_k(
    const u16* __restrict__ qkv, const u16* __restrict__ vtg,
    const unsigned char* __restrict__ mask, u16* __restrict__ ob)
{
    __shared__ u16 Klds[448 * 32];
    __shared__ u16 Plds[4][16 * 68];
    const int tid = threadIdx.x, w = tid >> 6, lane = tid & 63;
    const int lm = lane & 15, lk = lane >> 4;
    const int bid = blockIdx.x;
    const int bh = bid & 255, sg = bid >> 8;
    const int b = bh >> 3, h = bh & 7;
    const size_t rowbase = (size_t)b * LSEQ;

#pragma unroll
    for (int i = 0; i < 7; ++i) {
        int seg = w * 7 + i;
        gload16(qkv + (rowbase + seg * 16 + (lane >> 2)) * 768 + 256 + h * 32 + (lane & 3) * 8,
                &Klds[seg * 512]);
    }
    unsigned mbits = 0;
#pragma unroll
    for (int t = 0; t < 28; ++t)
        mbits |= (mask[b * LSEQ + t * 16 + lm] ? 1u : 0u) << t;
    __syncthreads();

    const u16* Vb = vtg + (size_t)bh * 32 * 448;
    f32x4 zz = {0.f, 0.f, 0.f, 0.f};

    const int q0 = (sg * 4 + w) * 16;
    bf16x8 qf = *(const bf16x8*)(qkv + (rowbase + q0 + lm) * 768 + h * 32 + lk * 8);

    f32x4 oacc[2] = {zz, zz};
    float sum[4] = {0.f, 0.f, 0.f, 0.f};
    u16* P = &Plds[w][0];
#pragma unroll
    for (int cc = 0; cc < 7; ++cc) {
#pragma unroll
        for (int tt = 0; tt < 4; ++tt) {
            int t = cc*4 + tt;
            bf16x8 kf = *(const bf16x8*)&Klds[(t*16 + lm)*32 + lk*8];
            f32x4 s = __builtin_amdgcn_mfma_f32_16x16x32_bf16(qf, kf, zz, 0, 0, 0);
            bool m = (mbits >> t) & 1;
#pragma unroll
            for (int r = 0; r < 4; ++r) {
                float e = m ? 0.f : exp2f(s[r]);
                sum[r] += e;
                P[(lk*4 + r)*68 + tt*16 + lm] = f2bf(e);
            }
        }
        bf16x8 pa0 = *(const bf16x8*)&P[lm*68 + lk*8];
        bf16x8 pa1 = *(const bf16x8*)&P[lm*68 + 32 + lk*8];
#pragma unroll
        for (int dt = 0; dt < 2; ++dt) {
            bf16x8 vb0 = *(const bf16x8*)(Vb + (size_t)(dt*16 + lm)*448 + cc*64 + lk*8);
            bf16x8 vb1 = *(const bf16x8*)(Vb + (size_t)(dt*16 + lm)*448 + cc*64 + 32 + lk*8);
            oacc[dt] = __builtin_amdgcn_mfma_f32_16x16x32_bf16(pa0, vb0, oacc[dt], 0, 0, 0);
            oacc[dt] = __builtin_amdgcn_mfma_f32_16x16x32_bf16(pa1, vb1, oacc[dt], 0, 0, 0);
        }
    }
#pragma unroll
    for (int off = 1; off < 16; off <<= 1)
#pragma unroll
        for (int r = 0; r < 4; ++r) sum[r] += __shfl_xor(sum[r], off);
    float inv[4];
#pragma unroll
    for (int r = 0; r < 4; ++r) inv[r] = 1.0f / sum[r];

#pragma unroll
    for (int dt = 0; dt < 2; ++dt)
#pragma unroll
        for (int r = 0; r < 4; ++r)
            ob[(rowbase + q0 + lk*4 + r)*256 + h*32 + dt*16 + lm] = f2bf(oacc[dt][r] * inv[r]);
}

// ---------------------------------------------------------------------------
extern "C" void kernel_launch(void* const* d_in, const int* in_sizes, int n_in,
                              void* d_out, int out_size, void* d_ws, size_t ws_size,
                              hipStream_t stream)
{
    const float* x_in = (const float*)d_in[0];
    const unsigned char* mask = (const unsigned char*)d_in[1];
    const float* pe   = (const float*)d_in[2];
    const float* Wq = (const float*)d_in[3];
    const float* bq = (const float*)d_in[4];
    const float* Wk = (const float*)d_in[5];
    const float* bk = (const float*)d_in[6];
    const float* Wv = (const float*)d_in[7];
    const float* bv = (const float*)d_in[8];
    const float* Wo = (const float*)d_in[9];
    const float* bo = (const float*)d_in[10];
    const float* W1 = (const float*)d_in[11];
    const float* bf1 = (const float*)d_in[12];
    const float* W2 = (const float*)d_in[13];
    const float* bf2 = (const float*)d_in[14];
    const float* ln1_g = (const float*)d_in[15];
    const float* ln1_b = (const float*)d_in[16];
    const float* ln2_g = (const float*)d_in[17];
    const float* ln2_b = (const float*)d_in[18];

    float* x = (float*)d_out;                 // fp32 residual stream [M,256]
    u16* ws = (u16*)d_ws;
    u16* nx   = ws;                           //  [M,256] bf16
    u16* qkv  = nx + 3670016;                 //  [M,768] bf16 (Q pre-scaled; V cols -> vtg)
    u16* ob   = qkv + 11010048;               //  [M,256] bf16
    u16* vtg  = ob + 3670016;                 //  [b,h,32,448] bf16
    u16* hb   = qkv;                          //  [M,1024] bf16 (aliases qkv+ob)
    u16* wqkvt = vtg + 3670016;               //  [12][768][256]
    u16* wot  = wqkvt + 2359296;              //  [12][256][256]
    u16* w1t  = wot + 786432;                 //  [12][1024][256]
    u16* w2t  = w1t + 3145728;                //  [12][256][1024]
    float* bqkv = (float*)(w2t + 3145728);    //  [12][768]

    twt_k<<<dim3(8, 8, NL), 256, 0, stream>>>(Wq, wqkvt,          256, 256, 65536, 196608);
    twt_k<<<dim3(8, 8, NL), 256, 0, stream>>>(Wk, wqkvt + 65536,  256, 256, 65536, 196608);
    twt_k<<<dim3(8, 8, NL), 256, 0, stream>>>(Wv, wqkvt + 131072, 256, 256, 65536, 196608);
    twt_k<<<dim3(8, 8, NL), 256, 0, stream>>>(Wo, wot, 256, 256, 65536, 65536);
    twt_k<<<dim3(32, 8, NL), 256, 0, stream>>>(W1, w1t, 256, 1024, 262144, 262144);
    twt_k<<<dim3(8, 32, NL), 256, 0, stream>>>(W2, w2t, 1024, 256, 262144, 262144);
    pack_bias_k<<<(NL * 768 + 255) / 256, 256, 0, stream>>>(bq, bk, bv, bqkv);

    ln0_k<<<MTOK / 4, 256, 0, stream>>>(x_in, pe, ln1_g, ln1_b, x, nx);

    for (int l = 0; l < NL; ++l) {
        mm_k<3><<<dim3(112, 6), 256, 0, stream>>>(
            nx, 256, wqkvt + (size_t)l*196608, bqkv + l*768, qkv, 768, 256, vtg);
        attn_k<<<1792, 256, 0, stream>>>(qkv, vtg, mask, ob);
        // oproj + residual + fused LN2 -> nx
        mmrow_k<true><<<224, 256, 0, stream>>>(
            ob, 256, wot + (size_t)l*65536, bo + l*256, x,
            ln2_g + l*256, ln2_b + l*256, nx, 256);
        mm_k<1><<<dim3(112, 8), 256, 0, stream>>>(
            nx, 256, w1t + (size_t)l*262144, bf1 + l*1024, hb, 1024, 256, nullptr);
        // ff2 + residual + fused LN1(next layer) -> nx  (last layer: no LN)
        if (l < NL - 1) {
            mmrow_k<true><<<224, 256, 0, stream>>>(
                hb, 1024, w2t + (size_t)l*262144, bf2 + l*256, x,
                ln1_g + (l+1)*256, ln1_b + (l+1)*256, nx, 1024);
        } else {
            mmrow_k<false><<<224, 256, 0, stream>>>(
                hb, 1024, w2t + (size_t)l*262144, bf2 + l*256, x,
                nullptr, nullptr, nullptr, 1024);
        }
    }
}